// Round 2
// baseline (313.268 us; speedup 1.0000x reference)
//
#include <hip/hip_runtime.h>
#include <math.h>

static constexpr float kL1   = 0.5f;
static constexpr float kL2   = 1.5f;
static constexpr float kBeta = 50000000.0f;
static constexpr float kEps  = 1e-08f;

__device__ __forceinline__ float waveSum(float v) {
#pragma unroll
    for (int off = 32; off > 0; off >>= 1) v += __shfl_xor(v, off, 64);
    return v;
}

// sum within each 16-lane group (4 steps instead of 6)
__device__ __forceinline__ float groupSum16(float v) {
#pragma unroll
    for (int off = 8; off > 0; off >>= 1) v += __shfl_xor(v, off, 64);
    return v;
}

__global__ __launch_bounds__(256) void fused_loss_kernel(
    const float* __restrict__ fusion_out, const float* __restrict__ comple_out,
    const float* __restrict__ labels,     const float* __restrict__ labels_enc,
    const float* __restrict__ xA,  const float* __restrict__ xAr,
    const float* __restrict__ xB,  const float* __restrict__ xBr,
    const float* __restrict__ xC,  const float* __restrict__ xCr,
    const float* __restrict__ mu,  const float* __restrict__ logvar,
    float* __restrict__ out,
    int B, int C, int D, int Z,
    int tubeBlocks, int klBlocks, int ceBlocks)
{
    const int lane = threadIdx.x & 63;
    const int wave = threadIdx.x >> 6;
    const int wavesPerBlock = blockDim.x >> 6;
    const int bid = blockIdx.x;

    float my = 0.0f;

    if (bid < tubeBlocks) {
        // ---- TUBE: 16 lanes per row, 4 rows per wave, one shot per group ----
        const int sub   = lane & 15;       // sublane within 16-lane group
        const int grp   = lane >> 4;       // group 0..3 within wave
        const int globalGroup = (bid * wavesPerBlock + wave) * 4 + grp;
        const int totalGroups = tubeBlocks * wavesPerBlock * 4;
        const int totalRows   = 4 * B;
        const int k16 = D >> 6;            // float4s per lane (=8 for D=512)
        float acc = 0.0f;
        for (int row = globalGroup; row < totalRows; row += totalGroups) {
            const int pair = row / B;
            const int r    = row - pair * B;
            const float* att; const float* lab;
            if      (pair == 0) { att = xAr;        lab = xA;         }
            else if (pair == 1) { att = xBr;        lab = xB;         }
            else if (pair == 2) { att = xCr;        lab = xC;         }
            else                { att = comple_out; lab = labels_enc; }
            const float4* a4 = (const float4*)(att + (size_t)r * D);
            const float4* l4 = (const float4*)(lab + (size_t)r * D);
            float dot = 0.f, pp = 0.f, gg = 0.f;
#pragma unroll
            for (int k = 0; k < 8; ++k) {
                if (k < k16) {
                    float4 a = a4[sub + 16 * k];
                    float4 l = l4[sub + 16 * k];
                    dot += a.x * l.x + a.y * l.y + a.z * l.z + a.w * l.w;
                    pp  += a.x * a.x + a.y * a.y + a.z * a.z + a.w * a.w;
                    gg  += l.x * l.x + l.y * l.y + l.z * l.z + l.w * l.w;
                }
            }
            dot = groupSum16(dot);
            pp  = groupSum16(pp);
            gg  = groupSum16(gg);
            if (sub == 0) {
                float p_norm = sqrtf(pp);
                float g_norm = sqrtf(gg);
                float denom  = p_norm * g_norm;
                float cosine = (denom == 0.0f) ? 0.0f : dot / denom;
                float s_s    = 1.0f - cosine * cosine;
                float sine   = (s_s < 0.0f) ? 0.0f
                             : sqrtf((s_s <= 0.0f) ? kEps : s_s);
                float gd     = (g_norm == 0.0f) ? (g_norm + kEps) : g_norm;
                float pc     = p_norm * cosine;
                float r_all  = pc / gd;
                float base   = p_norm * sine + fabsf(g_norm - pc);
                float ds     = (r_all >= 1.0f) ? (kL1 * base)
                             : ((r_all >= 0.0f) ? base
                                                : kL2 * fabsf(pc - g_norm - p_norm * sine));
                // -log(tanh(t)) = log((1+e^{-2t})/(1-e^{-2t}))
                float t  = 1.0f / ds;
                float em = __expf(-2.0f * t);
                acc += __logf(1.0f + em) - __logf(fmaxf(1.0f - em, 1e-30f));
            }
        }
        my = acc / (float)B;
    } else if (bid < tubeBlocks + klBlocks) {
        // ---------------- KL over mu/logvar ----------------
        const int b2 = bid - tubeBlocks;
        const int n4 = (B * Z) >> 2;
        const float4* mu4 = (const float4*)mu;
        const float4* lv4 = (const float4*)logvar;
        const int tid    = b2 * blockDim.x + threadIdx.x;
        const int stride = klBlocks * blockDim.x;
        float acc = 0.0f;
        for (int i = tid; i < n4; i += stride) {
            float4 m = mu4[i];
            float4 l = lv4[i];
            acc += (1.0f + l.x - m.x * m.x - __expf(l.x));
            acc += (1.0f + l.y - m.y * m.y - __expf(l.y));
            acc += (1.0f + l.z - m.z * m.z - __expf(l.z));
            acc += (1.0f + l.w - m.w * m.w - __expf(l.w));
        }
        my = acc * (-0.5f * kBeta / (float)(B * Z));
    } else {
        // ---------------- Cross-entropy: one wave per row over C=100 ----------------
        const int b3 = bid - tubeBlocks - klBlocks;
        const int globalWave = b3 * wavesPerBlock + wave;
        const int totalWaves = ceBlocks * wavesPerBlock;
        float acc = 0.0f;
        for (int r = globalWave; r < B; r += totalWaves) {
            const float* lrow = labels     + (size_t)r * C;
            const float* frow = fusion_out + (size_t)r * C;
            const bool has0 = (lane < C);
            const bool has1 = (lane + 64 < C);
            float v0 = has0 ? lrow[lane]      : -INFINITY;
            float v1 = has1 ? lrow[lane + 64] : -INFINITY;
            float f0 = has0 ? frow[lane]      : -INFINITY;
            float f1 = has1 ? frow[lane + 64] : -INFINITY;
            // local argmax, first-index-wins (idx lane < lane+64, so v0 wins ties)
            float bv; int bi;
            if (v1 > v0) { bv = v1; bi = lane + 64; } else { bv = v0; bi = lane; }
#pragma unroll
            for (int off = 32; off > 0; off >>= 1) {
                float ov = __shfl_xor(bv, off, 64);
                int   oi = __shfl_xor(bi, off, 64);
                if (ov > bv || (ov == bv && oi < bi)) { bv = ov; bi = oi; }
            }
            float m = fmaxf(f0, f1);
#pragma unroll
            for (int off = 32; off > 0; off >>= 1) m = fmaxf(m, __shfl_xor(m, off, 64));
            float e = 0.0f;
            if (has0) e += __expf(f0 - m);
            if (has1) e += __expf(f1 - m);
            e = waveSum(e);
            float t = (bi < 64) ? __shfl(f0, bi, 64) : __shfl(f1, bi - 64, 64);
            if (lane == 0) acc += -(t - m - __logf(e));
        }
        my = acc / (float)B;
    }

    // ---------------- block reduce + one atomic per block ----------------
    float s = waveSum(my);
    __shared__ float sw[8];
    if (lane == 0) sw[wave] = s;
    __syncthreads();
    if (threadIdx.x == 0) {
        float tot = 0.0f;
        for (int i = 0; i < wavesPerBlock; ++i) tot += sw[i];
        atomicAdd(out, tot);
    }
}

extern "C" void kernel_launch(void* const* d_in, const int* in_sizes, int n_in,
                              void* d_out, int out_size, void* d_ws, size_t ws_size,
                              hipStream_t stream) {
    const float* fusion_out = (const float*)d_in[0];
    const float* comple_out = (const float*)d_in[1];
    const float* labels     = (const float*)d_in[2];
    const float* labels_enc = (const float*)d_in[3];
    const float* xA  = (const float*)d_in[4];
    const float* xAr = (const float*)d_in[5];
    const float* xB  = (const float*)d_in[6];
    const float* xBr = (const float*)d_in[7];
    const float* xC  = (const float*)d_in[8];
    const float* xCr = (const float*)d_in[9];
    const float* mu  = (const float*)d_in[10];
    const float* lv  = (const float*)d_in[11];
    float* out = (float*)d_out;

    const int B = 16384;
    const int C = in_sizes[0] / B;    // 100
    const int D = in_sizes[1] / B;    // 512
    const int Z = in_sizes[10] / B;   // 128

    const int tubeBlocks = 4096;      // 4096*4 waves * 4 groups = 65536 rows, 1 row/group
    const int klBlocks   = 512;
    const int ceBlocks   = 2048;      // 8192 waves -> 2 rows/wave
    const int totalBlocks = tubeBlocks + klBlocks + ceBlocks;

    hipMemsetAsync(out, 0, sizeof(float), stream);
    fused_loss_kernel<<<totalBlocks, 256, 0, stream>>>(
        fusion_out, comple_out, labels, labels_enc,
        xA, xAr, xB, xBr, xC, xCr, mu, lv,
        out, B, C, D, Z, tubeBlocks, klBlocks, ceBlocks);
}

// Round 3
// 288.055 us; speedup vs baseline: 1.0875x; 1.0875x over previous
//
#include <hip/hip_runtime.h>
#include <math.h>

static constexpr float kL1   = 0.5f;
static constexpr float kL2   = 1.5f;
static constexpr float kBeta = 50000000.0f;
static constexpr float kEps  = 1e-08f;

__device__ __forceinline__ float waveSum(float v) {
#pragma unroll
    for (int off = 32; off > 0; off >>= 1) v += __shfl_xor(v, off, 64);
    return v;
}

__device__ __forceinline__ float tubeTail(float dot, float pp, float gg) {
    float p_norm = sqrtf(pp);
    float g_norm = sqrtf(gg);
    float denom  = p_norm * g_norm;
    float cosine = (denom == 0.0f) ? 0.0f : dot / denom;
    float s_s    = 1.0f - cosine * cosine;
    float sine   = (s_s < 0.0f) ? 0.0f : sqrtf((s_s <= 0.0f) ? kEps : s_s);
    float gd     = (g_norm == 0.0f) ? (g_norm + kEps) : g_norm;
    float pc     = p_norm * cosine;
    float r_all  = pc / gd;
    float base   = p_norm * sine + fabsf(g_norm - pc);
    float ds     = (r_all >= 1.0f) ? (kL1 * base)
                 : ((r_all >= 0.0f) ? base
                                    : kL2 * fabsf(pc - g_norm - p_norm * sine));
    // -log(tanh(t)) = log(1+e^{-2t}) - log(1-e^{-2t})
    float t  = 1.0f / ds;
    float em = __expf(-2.0f * t);
    return __logf(1.0f + em) - __logf(fmaxf(1.0f - em, 1e-30f));
}

__global__ __launch_bounds__(256) void fused_loss_partials(
    const float* __restrict__ fusion_out, const float* __restrict__ comple_out,
    const float* __restrict__ labels,     const float* __restrict__ labels_enc,
    const float* __restrict__ xA,  const float* __restrict__ xAr,
    const float* __restrict__ xB,  const float* __restrict__ xBr,
    const float* __restrict__ xC,  const float* __restrict__ xCr,
    const float* __restrict__ mu,  const float* __restrict__ logvar,
    float* __restrict__ partials,
    int B, int C, int Z,
    int tubeBlocks, int klBlocks, int ceBlocks)
{
    const int lane = threadIdx.x & 63;
    const int wave = threadIdx.x >> 6;
    const int wavesPerBlock = blockDim.x >> 6;
    const int bid = blockIdx.x;
    const int D = 512;                    // compile-time: unconditional batched loads

    float my = 0.0f;

    if (bid < tubeBlocks) {
        // ---- TUBE: one wave per row (1KB/instr coalescing), 2 rows per iter ----
        const int globalWave = bid * wavesPerBlock + wave;
        const int totalWaves = tubeBlocks * wavesPerBlock;   // 16384
        const int totalRows  = 4 * B;                        // 65536
        const float* atts[4] = { xAr, xBr, xCr, comple_out };
        const float* labs[4] = { xA,  xB,  xC,  labels_enc  };
        float acc = 0.0f;
        for (int row = globalWave; row < totalRows; row += 2 * totalWaves) {
            const int row2 = row + totalWaves;
            const int p0 = row  >> 14, r0 = row  & (B - 1);   // B = 16384
            const int p1 = row2 >> 14, r1 = row2 & (B - 1);
            const float4* a0 = (const float4*)(atts[p0] + (size_t)r0 * D);
            const float4* l0 = (const float4*)(labs[p0] + (size_t)r0 * D);
            const float4* a1 = (const float4*)(atts[p1] + (size_t)r1 * D);
            const float4* l1 = (const float4*)(labs[p1] + (size_t)r1 * D);
            // batch all 8 loads before any use
            float4 A0 = a0[lane], A1 = a0[lane + 64];
            float4 L0 = l0[lane], L1 = l0[lane + 64];
            float4 A2 = a1[lane], A3 = a1[lane + 64];
            float4 L2 = l1[lane], L3 = l1[lane + 64];
            float dotA = A0.x*L0.x + A0.y*L0.y + A0.z*L0.z + A0.w*L0.w
                       + A1.x*L1.x + A1.y*L1.y + A1.z*L1.z + A1.w*L1.w;
            float ppA  = A0.x*A0.x + A0.y*A0.y + A0.z*A0.z + A0.w*A0.w
                       + A1.x*A1.x + A1.y*A1.y + A1.z*A1.z + A1.w*A1.w;
            float ggA  = L0.x*L0.x + L0.y*L0.y + L0.z*L0.z + L0.w*L0.w
                       + L1.x*L1.x + L1.y*L1.y + L1.z*L1.z + L1.w*L1.w;
            float dotB = A2.x*L2.x + A2.y*L2.y + A2.z*L2.z + A2.w*L2.w
                       + A3.x*L3.x + A3.y*L3.y + A3.z*L3.z + A3.w*L3.w;
            float ppB  = A2.x*A2.x + A2.y*A2.y + A2.z*A2.z + A2.w*A2.w
                       + A3.x*A3.x + A3.y*A3.y + A3.z*A3.z + A3.w*A3.w;
            float ggB  = L2.x*L2.x + L2.y*L2.y + L2.z*L2.z + L2.w*L2.w
                       + L3.x*L3.x + L3.y*L3.y + L3.z*L3.z + L3.w*L3.w;
            // two independent butterfly sets -> ILP on the DS pipe
#pragma unroll
            for (int off = 32; off > 0; off >>= 1) {
                dotA += __shfl_xor(dotA, off, 64);
                ppA  += __shfl_xor(ppA,  off, 64);
                ggA  += __shfl_xor(ggA,  off, 64);
                dotB += __shfl_xor(dotB, off, 64);
                ppB  += __shfl_xor(ppB,  off, 64);
                ggB  += __shfl_xor(ggB,  off, 64);
            }
            if (lane == 0) {
                acc += tubeTail(dotA, ppA, ggA);
                acc += tubeTail(dotB, ppB, ggB);
            }
        }
        my = acc / (float)B;
    } else if (bid < tubeBlocks + klBlocks) {
        // ---------------- KL over mu/logvar ----------------
        const int b2 = bid - tubeBlocks;
        const int n4 = (B * Z) >> 2;
        const float4* mu4 = (const float4*)mu;
        const float4* lv4 = (const float4*)logvar;
        const int tid    = b2 * blockDim.x + threadIdx.x;
        const int stride = klBlocks * blockDim.x;
        float acc = 0.0f;
        for (int i = tid; i < n4; i += stride) {
            float4 m = mu4[i];
            float4 l = lv4[i];
            acc += (1.0f + l.x - m.x * m.x - __expf(l.x));
            acc += (1.0f + l.y - m.y * m.y - __expf(l.y));
            acc += (1.0f + l.z - m.z * m.z - __expf(l.z));
            acc += (1.0f + l.w - m.w * m.w - __expf(l.w));
        }
        my = acc * (-0.5f * kBeta / (float)(B * Z));
    } else {
        // ---------------- Cross-entropy: one wave per row over C=100 ----------------
        const int b3 = bid - tubeBlocks - klBlocks;
        const int globalWave = b3 * wavesPerBlock + wave;
        const int totalWaves = ceBlocks * wavesPerBlock;
        float acc = 0.0f;
        for (int r = globalWave; r < B; r += totalWaves) {
            const float* lrow = labels     + (size_t)r * C;
            const float* frow = fusion_out + (size_t)r * C;
            const bool has0 = (lane < C);
            const bool has1 = (lane + 64 < C);
            float v0 = has0 ? lrow[lane]      : -INFINITY;
            float v1 = has1 ? lrow[lane + 64] : -INFINITY;
            float f0 = has0 ? frow[lane]      : -INFINITY;
            float f1 = has1 ? frow[lane + 64] : -INFINITY;
            float bv; int bi;
            if (v1 > v0) { bv = v1; bi = lane + 64; } else { bv = v0; bi = lane; }
#pragma unroll
            for (int off = 32; off > 0; off >>= 1) {
                float ov = __shfl_xor(bv, off, 64);
                int   oi = __shfl_xor(bi, off, 64);
                if (ov > bv || (ov == bv && oi < bi)) { bv = ov; bi = oi; }
            }
            float m = fmaxf(f0, f1);
#pragma unroll
            for (int off = 32; off > 0; off >>= 1) m = fmaxf(m, __shfl_xor(m, off, 64));
            float e = 0.0f;
            if (has0) e += __expf(f0 - m);
            if (has1) e += __expf(f1 - m);
            e = waveSum(e);
            float t = (bi < 64) ? __shfl(f0, bi, 64) : __shfl(f1, bi - 64, 64);
            if (lane == 0) acc += -(t - m - __logf(e));
        }
        my = acc / (float)B;
    }

    // ---------------- block reduce -> per-block partial (NO atomics) ----------------
    float s = waveSum(my);
    __shared__ float sw[8];
    if (lane == 0) sw[wave] = s;
    __syncthreads();
    if (threadIdx.x == 0) {
        float tot = 0.0f;
        for (int i = 0; i < wavesPerBlock; ++i) tot += sw[i];
        partials[bid] = tot;
    }
}

__global__ __launch_bounds__(256) void reduce_partials(
    const float* __restrict__ partials, float* __restrict__ out, int n)
{
    float s = 0.0f;
    for (int i = threadIdx.x; i < n; i += 256) s += partials[i];
    s = waveSum(s);
    __shared__ float sw[4];
    const int lane = threadIdx.x & 63;
    const int wave = threadIdx.x >> 6;
    if (lane == 0) sw[wave] = s;
    __syncthreads();
    if (threadIdx.x == 0) out[0] = sw[0] + sw[1] + sw[2] + sw[3];
}

extern "C" void kernel_launch(void* const* d_in, const int* in_sizes, int n_in,
                              void* d_out, int out_size, void* d_ws, size_t ws_size,
                              hipStream_t stream) {
    const float* fusion_out = (const float*)d_in[0];
    const float* comple_out = (const float*)d_in[1];
    const float* labels     = (const float*)d_in[2];
    const float* labels_enc = (const float*)d_in[3];
    const float* xA  = (const float*)d_in[4];
    const float* xAr = (const float*)d_in[5];
    const float* xB  = (const float*)d_in[6];
    const float* xBr = (const float*)d_in[7];
    const float* xC  = (const float*)d_in[8];
    const float* xCr = (const float*)d_in[9];
    const float* mu  = (const float*)d_in[10];
    const float* lv  = (const float*)d_in[11];
    float* out = (float*)d_out;
    float* ws  = (float*)d_ws;

    const int B = 16384;
    const int C = in_sizes[0] / B;    // 100
    const int Z = in_sizes[10] / B;   // 128

    const int tubeBlocks = 4096;
    const int klBlocks   = 512;
    const int ceBlocks   = 2048;
    const int totalBlocks = tubeBlocks + klBlocks + ceBlocks;

    fused_loss_partials<<<totalBlocks, 256, 0, stream>>>(
        fusion_out, comple_out, labels, labels_enc,
        xA, xAr, xB, xBr, xC, xCr, mu, lv,
        ws, B, C, Z, tubeBlocks, klBlocks, ceBlocks);
    reduce_partials<<<1, 256, 0, stream>>>(ws, out, totalBlocks);
}